// Round 1
// baseline (2242.239 us; speedup 1.0000x reference)
//
#include <hip/hip_runtime.h>

// Activations kept in batch-last layout [features, Bc]: lane index = batch ->
// fully coalesced loads/stores; per-position LC weights are wave-uniform.

// ---------------- transpose x[B,784] chunk -> xT[784, Bc] ----------------
__global__ __launch_bounds__(256) void k_tr(const float* __restrict__ x,
                                            float* __restrict__ xT, int Bc) {
  __shared__ float t[32][33];
  const int b0 = blockIdx.x * 32;
  const int f0 = blockIdx.y * 32;
  const int tx = threadIdx.x, ty = threadIdx.y;
  for (int r = ty; r < 32; r += 8) {
    const int f = f0 + tx;
    t[r][tx] = (f < 784) ? x[(size_t)(b0 + r) * 784 + f] : 0.f;
  }
  __syncthreads();
  for (int r = ty; r < 32; r += 8) {
    const int f = f0 + r;
    if (f < 784) xT[(size_t)f * Bc + b0 + tx] = t[tx][r];
  }
}

// ---------------- generic locally-connected layer ----------------
// in : [C*Hi*Wi, Bc]   w : [O, C, Ho, Wo, 9]   bias : [O, Ho, Wo]
// out: [O*Ho*Wo, Bc]
template <int C, int Hi, int Wi, int O, int Ho, int Wo, int S, bool RELU>
__global__ __launch_bounds__(256) void k_lc(const float* __restrict__ in,
                                            const float* __restrict__ w,
                                            const float* __restrict__ bias,
                                            float* __restrict__ out, int Bc) {
  const int b = blockIdx.x * 64 + threadIdx.x;
  const int f = blockIdx.y * 4 + threadIdx.y;
  const int HW = Ho * Wo;
  if (f >= O * HW) return;
  const int o = f / HW, rem = f - o * HW;
  const int ho = rem / Wo, wo = rem - ho * Wo;
  float acc = bias[f];
  const float* ip = in + ((size_t)(ho * S) * Wi + wo * S) * Bc + b;
  const float* wp = w + ((size_t)o * C * HW + rem) * 9;
  for (int c = 0; c < C; ++c) {
    const float* ic = ip + (size_t)c * Hi * Wi * Bc;
    const float* wc = wp + (size_t)c * HW * 9;
#pragma unroll
    for (int kh = 0; kh < 3; ++kh)
#pragma unroll
      for (int kw = 0; kw < 3; ++kw)
        acc = fmaf(ic[(size_t)(kh * Wi + kw) * Bc], wc[kh * 3 + kw], acc);
  }
  out[(size_t)f * Bc + b] = RELU ? fmaxf(acc, 0.f) : acc;
}

// ---------------- FC1: out[512,Bc] = relu(fw1[512,1024] @ in[1024,Bc] + fb1)
// block: 64x4 threads; each thread: 8 j's x 4 b-columns (register blocking).
__global__ __launch_bounds__(256) void k_fc1(const float* __restrict__ in,
                                             const float* __restrict__ fw1,
                                             const float* __restrict__ fb1,
                                             float* __restrict__ out, int Bc) {
  __shared__ float wt[32][128];  // 16 KB weight tile
  const int tx = threadIdx.x, ty = threadIdx.y;
  const int tid = ty * 64 + tx;
  const int bbase = blockIdx.x * 256 + tx;  // + bb*64
  const int j0 = blockIdx.y * 32;
  float acc[8][4];
#pragma unroll
  for (int jj = 0; jj < 8; ++jj)
#pragma unroll
    for (int bb = 0; bb < 4; ++bb) acc[jj][bb] = 0.f;

  for (int k0 = 0; k0 < 1024; k0 += 128) {
    __syncthreads();
#pragma unroll
    for (int i = 0; i < 16; ++i) {
      const int idx = i * 256 + tid;
      wt[idx >> 7][idx & 127] =
          fw1[(size_t)(j0 + (idx >> 7)) * 1024 + k0 + (idx & 127)];
    }
    __syncthreads();
    for (int k = 0; k < 128; ++k) {
      float v[4];
#pragma unroll
      for (int bb = 0; bb < 4; ++bb)
        v[bb] = in[(size_t)(k0 + k) * Bc + bbase + bb * 64];
#pragma unroll
      for (int jj = 0; jj < 8; ++jj) {
        const float wv = wt[ty * 8 + jj][k];  // wave-uniform broadcast
#pragma unroll
        for (int bb = 0; bb < 4; ++bb) acc[jj][bb] = fmaf(v[bb], wv, acc[jj][bb]);
      }
    }
  }
#pragma unroll
  for (int jj = 0; jj < 8; ++jj) {
    const int j = j0 + ty * 8 + jj;
    const float bj = fb1[j];
#pragma unroll
    for (int bb = 0; bb < 4; ++bb)
      out[(size_t)j * Bc + bbase + bb * 64] = fmaxf(acc[jj][bb] + bj, 0.f);
  }
}

// ---------------- FC2: out[b,10] = fw2[10,512] @ in[512,Bc] + fb2 ----------
__global__ __launch_bounds__(256) void k_fc2(const float* __restrict__ in,
                                             const float* __restrict__ fw2,
                                             const float* __restrict__ fb2,
                                             float* __restrict__ out, int Bc,
                                             int b0) {
  __shared__ float w[10][512];  // 20 KB
  __shared__ float bias[10];
  const int tid = threadIdx.x;
  for (int idx = tid; idx < 5120; idx += 256) w[idx >> 9][idx & 511] = fw2[idx];
  if (tid < 10) bias[tid] = fb2[tid];
  __syncthreads();
  const int b = blockIdx.x * 256 + tid;
  float acc[10];
#pragma unroll
  for (int i = 0; i < 10; ++i) acc[i] = bias[i];
  for (int j = 0; j < 512; ++j) {
    const float v = in[(size_t)j * Bc + b];
#pragma unroll
    for (int i = 0; i < 10; ++i) acc[i] = fmaf(v, w[i][j], acc[i]);
  }
#pragma unroll
  for (int i = 0; i < 10; ++i) out[(size_t)(b0 + b) * 10 + i] = acc[i];
}

extern "C" void kernel_launch(void* const* d_in, const int* in_sizes, int n_in,
                              void* d_out, int out_size, void* d_ws,
                              size_t ws_size, hipStream_t stream) {
  const float* x   = (const float*)d_in[0];
  const float* w1  = (const float*)d_in[1];
  const float* b1  = (const float*)d_in[2];
  const float* w2  = (const float*)d_in[3];
  const float* b2  = (const float*)d_in[4];
  const float* w3  = (const float*)d_in[5];
  const float* b3  = (const float*)d_in[6];
  const float* fw1 = (const float*)d_in[7];
  const float* fb1 = (const float*)d_in[8];
  const float* fw2 = (const float*)d_in[9];
  const float* fb2 = (const float*)d_in[10];
  float* out = (float*)d_out;

  const int B = in_sizes[0] / 784;  // 8192

  // ws layout per chunk: xT[784*Bc] | A[2704*Bc] | Bb[1152*Bc]
  const size_t per_elem = (size_t)(784 + 2704 + 1152) * sizeof(float);
  int Bc = B;
  while ((size_t)Bc * per_elem > ws_size && Bc > 256) Bc >>= 1;
  const int nch = B / Bc;

  float* xT = (float*)d_ws;
  float* A  = xT + (size_t)784 * Bc;
  float* Bb = A + (size_t)2704 * Bc;

  for (int ch = 0; ch < nch; ++ch) {
    const float* xc = x + (size_t)ch * Bc * 784;
    const int b0 = ch * Bc;

    k_tr<<<dim3(Bc / 32, 25), dim3(32, 8), 0, stream>>>(xc, xT, Bc);

    // LC1: [1,28,28] -> [16,13,13], stride 2, relu
    k_lc<1, 28, 28, 16, 13, 13, 2, true>
        <<<dim3(Bc / 64, 676), dim3(64, 4), 0, stream>>>(xT, w1, b1, A, Bc);
    // LC2: [16,13,13] -> [32,6,6], stride 2, relu
    k_lc<16, 13, 13, 32, 6, 6, 2, true>
        <<<dim3(Bc / 64, 288), dim3(64, 4), 0, stream>>>(A, w2, b2, Bb, Bc);
    // LC3: [32,6,6] -> [64,4,4], stride 1, no relu  (writes h3[1024,Bc] into A)
    k_lc<32, 6, 6, 64, 4, 4, 1, false>
        <<<dim3(Bc / 64, 256), dim3(64, 4), 0, stream>>>(Bb, w3, b3, A, Bc);

    // FC1: A[1024,Bc] -> Bb[512,Bc], relu
    k_fc1<<<dim3(Bc / 256, 16), dim3(64, 4), 0, stream>>>(A, fw1, fb1, Bb, Bc);
    // FC2: Bb[512,Bc] -> out[b,10]
    k_fc2<<<dim3(Bc / 256), 256, 0, stream>>>(Bb, fw2, fb2, out, Bc, b0);
  }
}

// Round 2
// 1038.278 us; speedup vs baseline: 2.1596x; 2.1596x over previous
//
#include <hip/hip_runtime.h>

#define RFL(x) __builtin_amdgcn_readfirstlane((int)(x))

// All activations in batch-last layout [feature, B]; lanes = batch (coalesced),
// weights addressed by wave-uniform indices (scalar loads).

// ---------------- transpose x[B,784] -> xT[784, Bc] ----------------
__global__ __launch_bounds__(256) void k_tr(const float* __restrict__ x,
                                            float* __restrict__ xT, int Bc) {
  __shared__ float t[32][33];
  const int b0 = blockIdx.x * 32;
  const int f0 = blockIdx.y * 32;
  const int tx = threadIdx.x, ty = threadIdx.y;
  for (int r = ty; r < 32; r += 8) {
    const int f = f0 + tx;
    t[r][tx] = (f < 784) ? x[(size_t)(b0 + r) * 784 + f] : 0.f;
  }
  __syncthreads();
  for (int r = ty; r < 32; r += 8) {
    const int f = f0 + r;
    if (f < 784) xT[(size_t)f * Bc + b0 + tx] = t[tx][r];
  }
}

// ---------------- LC1: [1,28,28] -> [16,13,13], stride 2, relu -------------
// grid (B/64, 13=ho), block (64,4). Wave: 4 o x 13 wo for one ho.
__global__ __launch_bounds__(256) void k_lc1(const float* __restrict__ in,
                                             const float* __restrict__ w,
                                             const float* __restrict__ bias,
                                             float* __restrict__ out, int B) {
  const int b = blockIdx.x * 64 + threadIdx.x;
  const int ho = blockIdx.y;
  const int o0 = RFL(threadIdx.y) * 4;
  float xv[3][27];
#pragma unroll
  for (int r = 0; r < 3; ++r)
#pragma unroll
    for (int col = 0; col < 27; ++col)
      xv[r][col] = in[(size_t)((2 * ho + r) * 28 + col) * B + b];
  float acc[4][13];
#pragma unroll
  for (int oo = 0; oo < 4; ++oo)
#pragma unroll
    for (int wo = 0; wo < 13; ++wo)
      acc[oo][wo] = bias[(o0 + oo) * 169 + ho * 13 + wo];
#pragma unroll
  for (int oo = 0; oo < 4; ++oo)
#pragma unroll
    for (int wo = 0; wo < 13; ++wo) {
      const float* wp = w + (size_t)((o0 + oo) * 169 + ho * 13 + wo) * 9;
#pragma unroll
      for (int kh = 0; kh < 3; ++kh)
#pragma unroll
        for (int kw = 0; kw < 3; ++kw)
          acc[oo][wo] = fmaf(xv[kh][2 * wo + kw], wp[kh * 3 + kw], acc[oo][wo]);
    }
#pragma unroll
  for (int oo = 0; oo < 4; ++oo)
#pragma unroll
    for (int wo = 0; wo < 13; ++wo)
      out[(size_t)((o0 + oo) * 169 + ho * 13 + wo) * B + b] =
          fmaxf(acc[oo][wo], 0.f);
}

// ---------------- LC2: [16,13,13] -> [32,6,6], stride 2, relu --------------
// grid (B/64, 4), block (64,4). Wave: 2 o x 36 rem. Loop c(16) x ho(6).
__global__ __launch_bounds__(256) void k_lc2(const float* __restrict__ in,
                                             const float* __restrict__ w,
                                             const float* __restrict__ bias,
                                             float* __restrict__ out, int B) {
  const int b = blockIdx.x * 64 + threadIdx.x;
  const int o0 = (blockIdx.y * 4 + RFL(threadIdx.y)) * 2;
  float acc[2][36];
#pragma unroll
  for (int oo = 0; oo < 2; ++oo)
#pragma unroll
    for (int r = 0; r < 36; ++r) acc[oo][r] = bias[(o0 + oo) * 36 + r];
  for (int c = 0; c < 16; ++c) {
    for (int ho = 0; ho < 6; ++ho) {
      float xv[3][13];
#pragma unroll
      for (int r = 0; r < 3; ++r)
#pragma unroll
        for (int col = 0; col < 13; ++col)
          xv[r][col] = in[(size_t)(c * 169 + (2 * ho + r) * 13 + col) * B + b];
#pragma unroll
      for (int oo = 0; oo < 2; ++oo)
#pragma unroll
        for (int wo = 0; wo < 6; ++wo) {
          const float* wp =
              w + (size_t)((((o0 + oo) * 16 + c) * 36) + ho * 6 + wo) * 9;
          float a = acc[oo][ho * 6 + wo];
#pragma unroll
          for (int kh = 0; kh < 3; ++kh)
#pragma unroll
            for (int kw = 0; kw < 3; ++kw)
              a = fmaf(xv[kh][2 * wo + kw], wp[kh * 3 + kw], a);
          acc[oo][ho * 6 + wo] = a;
        }
    }
  }
#pragma unroll
  for (int oo = 0; oo < 2; ++oo)
#pragma unroll
    for (int r = 0; r < 36; ++r)
      out[(size_t)((o0 + oo) * 36 + r) * B + b] = fmaxf(acc[oo][r], 0.f);
}

// ---------------- LC3: [32,6,6] -> [64,4,4], stride 1, no relu -------------
// grid (B/64, 4), block (64,4). Wave: 4 o x 16 rem. Loop c(32): 36 loads,
// 576 FMA.
__global__ __launch_bounds__(256) void k_lc3(const float* __restrict__ in,
                                             const float* __restrict__ w,
                                             const float* __restrict__ bias,
                                             float* __restrict__ out, int B) {
  const int b = blockIdx.x * 64 + threadIdx.x;
  const int o0 = (blockIdx.y * 4 + RFL(threadIdx.y)) * 4;
  float acc[4][16];
#pragma unroll
  for (int oo = 0; oo < 4; ++oo)
#pragma unroll
    for (int r = 0; r < 16; ++r) acc[oo][r] = bias[(o0 + oo) * 16 + r];
  for (int c = 0; c < 32; ++c) {
    float xv[36];
#pragma unroll
    for (int p = 0; p < 36; ++p) xv[p] = in[(size_t)(c * 36 + p) * B + b];
#pragma unroll
    for (int oo = 0; oo < 4; ++oo)
#pragma unroll
      for (int ho = 0; ho < 4; ++ho)
#pragma unroll
        for (int wo = 0; wo < 4; ++wo) {
          const float* wp =
              w + (size_t)((((o0 + oo) * 32 + c) * 16) + ho * 4 + wo) * 9;
          float a = acc[oo][ho * 4 + wo];
#pragma unroll
          for (int kh = 0; kh < 3; ++kh)
#pragma unroll
            for (int kw = 0; kw < 3; ++kw)
              a = fmaf(xv[(ho + kh) * 6 + wo + kw], wp[kh * 3 + kw], a);
          acc[oo][ho * 4 + wo] = a;
        }
  }
#pragma unroll
  for (int oo = 0; oo < 4; ++oo)
#pragma unroll
    for (int r = 0; r < 16; ++r)
      out[(size_t)((o0 + oo) * 16 + r) * B + b] = acc[oo][r];
}

// ---------------- FC1: h4[512,B] = relu(fw1[512,1024] @ h3[1024,B] + fb1) --
// grid (B/64, 4), block (64,4). Wave: 32 j. Per k: 1 load, 32 FMA.
__global__ __launch_bounds__(256) void k_fc1(const float* __restrict__ in,
                                             const float* __restrict__ fw1,
                                             const float* __restrict__ fb1,
                                             float* __restrict__ out, int B) {
  const int b = blockIdx.x * 64 + threadIdx.x;
  const int j0 = blockIdx.y * 128 + RFL(threadIdx.y) * 32;
  float acc[32];
#pragma unroll
  for (int jj = 0; jj < 32; ++jj) acc[jj] = 0.f;
  const float* wp = fw1 + (size_t)j0 * 1024;
#pragma unroll 4
  for (int k = 0; k < 1024; ++k) {
    const float v = in[(size_t)k * B + b];
#pragma unroll
    for (int jj = 0; jj < 32; ++jj)
      acc[jj] = fmaf(v, wp[(size_t)jj * 1024 + k], acc[jj]);
  }
#pragma unroll
  for (int jj = 0; jj < 32; ++jj)
    out[(size_t)(j0 + jj) * B + b] = fmaxf(acc[jj] + fb1[j0 + jj], 0.f);
}

// ---------------- FC2: out[b,10] = fw2[10,512] @ h4[512,B] + fb2 -----------
// grid (B/64), block (64,4). ty = k-quarter, LDS reduce.
__global__ __launch_bounds__(256) void k_fc2(const float* __restrict__ in,
                                             const float* __restrict__ fw2,
                                             const float* __restrict__ fb2,
                                             float* __restrict__ out, int B,
                                             int b0) {
  __shared__ float red[4][10][64];
  const int tx = threadIdx.x;
  const int b = blockIdx.x * 64 + tx;
  const int tyu = RFL(threadIdx.y);
  float acc[10];
#pragma unroll
  for (int i = 0; i < 10; ++i) acc[i] = 0.f;
  for (int kk = 0; kk < 128; ++kk) {
    const int k = tyu * 128 + kk;
    const float v = in[(size_t)k * B + b];
#pragma unroll
    for (int i = 0; i < 10; ++i) acc[i] = fmaf(v, fw2[i * 512 + k], acc[i]);
  }
#pragma unroll
  for (int i = 0; i < 10; ++i) red[tyu][i][tx] = acc[i];
  __syncthreads();
  if (threadIdx.y == 0) {
#pragma unroll
    for (int i = 0; i < 10; ++i) {
      const float s = fb2[i] + red[0][i][tx] + red[1][i][tx] + red[2][i][tx] +
                      red[3][i][tx];
      out[(size_t)(b0 + b) * 10 + i] = s;
    }
  }
}

extern "C" void kernel_launch(void* const* d_in, const int* in_sizes, int n_in,
                              void* d_out, int out_size, void* d_ws,
                              size_t ws_size, hipStream_t stream) {
  const float* x   = (const float*)d_in[0];
  const float* w1  = (const float*)d_in[1];
  const float* b1  = (const float*)d_in[2];
  const float* w2  = (const float*)d_in[3];
  const float* b2  = (const float*)d_in[4];
  const float* w3  = (const float*)d_in[5];
  const float* b3  = (const float*)d_in[6];
  const float* fw1 = (const float*)d_in[7];
  const float* fb1 = (const float*)d_in[8];
  const float* fw2 = (const float*)d_in[9];
  const float* fb2 = (const float*)d_in[10];
  float* out = (float*)d_out;

  const int B = in_sizes[0] / 784;  // 8192

  // ws regions per chunk (floats): P0 = 784 (xT, reused for h4[512]),
  // P1 = 2704 (h1, reused for h3[1024]), P2 = 1152 (h2). Total 4640/elem.
  const size_t per_elem = (size_t)(784 + 2704 + 1152) * sizeof(float);
  int Bc = B;
  while ((size_t)Bc * per_elem > ws_size && Bc > 512) Bc >>= 1;
  const int nch = B / Bc;

  float* P0 = (float*)d_ws;              // xT[784,Bc] then h4[512,Bc]
  float* P1 = P0 + (size_t)784 * Bc;     // h1[2704,Bc] then h3[1024,Bc]
  float* P2 = P1 + (size_t)2704 * Bc;    // h2[1152,Bc]

  for (int ch = 0; ch < nch; ++ch) {
    const float* xc = x + (size_t)ch * Bc * 784;
    const int b0 = ch * Bc;
    const int nb = Bc / 64;

    k_tr<<<dim3(Bc / 32, 25), dim3(32, 8), 0, stream>>>(xc, P0, Bc);
    k_lc1<<<dim3(nb, 13), dim3(64, 4), 0, stream>>>(P0, w1, b1, P1, Bc);
    k_lc2<<<dim3(nb, 4), dim3(64, 4), 0, stream>>>(P1, w2, b2, P2, Bc);
    k_lc3<<<dim3(nb, 4), dim3(64, 4), 0, stream>>>(P2, w3, b3, P1, Bc);
    k_fc1<<<dim3(nb, 4), dim3(64, 4), 0, stream>>>(P1, fw1, fb1, P0, Bc);
    k_fc2<<<dim3(nb), dim3(64, 4), 0, stream>>>(P0, fw2, fb2, out, Bc, b0);
  }
}

// Round 3
// 726.799 us; speedup vs baseline: 3.0851x; 1.4286x over previous
//
#include <hip/hip_runtime.h>

#define RFL(x) __builtin_amdgcn_readfirstlane((int)(x))

// All activations in batch-last layout [feature, B]; lanes = batch (coalesced).

// ---------------- transpose x[B,784] -> xT[784, Bc] ----------------
__global__ __launch_bounds__(256) void k_tr(const float* __restrict__ x,
                                            float* __restrict__ xT, int Bc) {
  __shared__ float t[32][33];
  const int b0 = blockIdx.x * 32;
  const int f0 = blockIdx.y * 32;
  const int tx = threadIdx.x, ty = threadIdx.y;
  for (int r = ty; r < 32; r += 8) {
    const int f = f0 + tx;
    t[r][tx] = (f < 784) ? x[(size_t)(b0 + r) * 784 + f] : 0.f;
  }
  __syncthreads();
  for (int r = ty; r < 32; r += 8) {
    const int f = f0 + r;
    if (f < 784) xT[(size_t)f * Bc + b0 + tx] = t[tx][r];
  }
}

// ---------------- LC1: [1,28,28] -> [16,13,13], stride 2, relu -------------
__global__ __launch_bounds__(256) void k_lc1(const float* __restrict__ in,
                                             const float* __restrict__ w,
                                             const float* __restrict__ bias,
                                             float* __restrict__ out, int B) {
  const int b = blockIdx.x * 64 + threadIdx.x;
  const int ho = blockIdx.y;
  const int o0 = RFL(threadIdx.y) * 4;
  float xv[3][27];
#pragma unroll
  for (int r = 0; r < 3; ++r)
#pragma unroll
    for (int col = 0; col < 27; ++col)
      xv[r][col] = in[(size_t)((2 * ho + r) * 28 + col) * B + b];
  float acc[4][13];
#pragma unroll
  for (int oo = 0; oo < 4; ++oo)
#pragma unroll
    for (int wo = 0; wo < 13; ++wo)
      acc[oo][wo] = bias[(o0 + oo) * 169 + ho * 13 + wo];
#pragma unroll
  for (int oo = 0; oo < 4; ++oo)
#pragma unroll
    for (int wo = 0; wo < 13; ++wo) {
      const float* wp = w + (size_t)((o0 + oo) * 169 + ho * 13 + wo) * 9;
#pragma unroll
      for (int kh = 0; kh < 3; ++kh)
#pragma unroll
        for (int kw = 0; kw < 3; ++kw)
          acc[oo][wo] = fmaf(xv[kh][2 * wo + kw], wp[kh * 3 + kw], acc[oo][wo]);
    }
#pragma unroll
  for (int oo = 0; oo < 4; ++oo)
#pragma unroll
    for (int wo = 0; wo < 13; ++wo)
      out[(size_t)((o0 + oo) * 169 + ho * 13 + wo) * B + b] =
          fmaxf(acc[oo][wo], 0.f);
}

// ---------------- LC2: [16,13,13] -> [32,6,6], stride 2, relu --------------
__global__ __launch_bounds__(256) void k_lc2(const float* __restrict__ in,
                                             const float* __restrict__ w,
                                             const float* __restrict__ bias,
                                             float* __restrict__ out, int B) {
  const int b = blockIdx.x * 64 + threadIdx.x;
  const int o0 = (blockIdx.y * 4 + RFL(threadIdx.y)) * 2;
  float acc[2][36];
#pragma unroll
  for (int oo = 0; oo < 2; ++oo)
#pragma unroll
    for (int r = 0; r < 36; ++r) acc[oo][r] = bias[(o0 + oo) * 36 + r];
  for (int c = 0; c < 16; ++c) {
    for (int ho = 0; ho < 6; ++ho) {
      float xv[3][13];
#pragma unroll
      for (int r = 0; r < 3; ++r)
#pragma unroll
        for (int col = 0; col < 13; ++col)
          xv[r][col] = in[(size_t)(c * 169 + (2 * ho + r) * 13 + col) * B + b];
#pragma unroll
      for (int oo = 0; oo < 2; ++oo)
#pragma unroll
        for (int wo = 0; wo < 6; ++wo) {
          const float* wp =
              w + (size_t)((((o0 + oo) * 16 + c) * 36) + ho * 6 + wo) * 9;
          float a = acc[oo][ho * 6 + wo];
#pragma unroll
          for (int kh = 0; kh < 3; ++kh)
#pragma unroll
            for (int kw = 0; kw < 3; ++kw)
              a = fmaf(xv[kh][2 * wo + kw], wp[kh * 3 + kw], a);
          acc[oo][ho * 6 + wo] = a;
        }
    }
  }
#pragma unroll
  for (int oo = 0; oo < 2; ++oo)
#pragma unroll
    for (int r = 0; r < 36; ++r)
      out[(size_t)((o0 + oo) * 36 + r) * B + b] = fmaxf(acc[oo][r], 0.f);
}

// ---------------- LC3: [32,6,6] -> [64,4,4], stride 1, no relu -------------
__global__ __launch_bounds__(256) void k_lc3(const float* __restrict__ in,
                                             const float* __restrict__ w,
                                             const float* __restrict__ bias,
                                             float* __restrict__ out, int B) {
  const int b = blockIdx.x * 64 + threadIdx.x;
  const int o0 = (blockIdx.y * 4 + RFL(threadIdx.y)) * 4;
  float acc[4][16];
#pragma unroll
  for (int oo = 0; oo < 4; ++oo)
#pragma unroll
    for (int r = 0; r < 16; ++r) acc[oo][r] = bias[(o0 + oo) * 16 + r];
  for (int c = 0; c < 32; ++c) {
    float xv[36];
#pragma unroll
    for (int p = 0; p < 36; ++p) xv[p] = in[(size_t)(c * 36 + p) * B + b];
#pragma unroll
    for (int oo = 0; oo < 4; ++oo)
#pragma unroll
      for (int ho = 0; ho < 4; ++ho)
#pragma unroll
        for (int wo = 0; wo < 4; ++wo) {
          const float* wp =
              w + (size_t)((((o0 + oo) * 32 + c) * 16) + ho * 4 + wo) * 9;
          float a = acc[oo][ho * 4 + wo];
#pragma unroll
          for (int kh = 0; kh < 3; ++kh)
#pragma unroll
            for (int kw = 0; kw < 3; ++kw)
              a = fmaf(xv[(ho + kh) * 6 + wo + kw], wp[kh * 3 + kw], a);
          acc[oo][ho * 4 + wo] = a;
        }
  }
#pragma unroll
  for (int oo = 0; oo < 4; ++oo)
#pragma unroll
    for (int r = 0; r < 16; ++r)
      out[(size_t)((o0 + oo) * 16 + r) * B + b] = acc[oo][r];
}

// ---------------- FC1: SGEMM h4[512,B] = relu(fw1[512,1024] @ h3[1024,B]) --
// Tile 128j x 128b, KT=16, 256 threads, thread = 8j x 8b, double-buffered LDS.
__global__ __launch_bounds__(256) void k_fc1(const float* __restrict__ in,
                                             const float* __restrict__ fw1,
                                             const float* __restrict__ fb1,
                                             float* __restrict__ out, int B) {
  __shared__ float Wt[2][16][128];  // [k][j] (transposed on store)
  __shared__ float At[2][16][128];  // [k][b]
  const int tid = threadIdx.x;
  const int tx = tid & 15, ty = tid >> 4;
  const int b0 = blockIdx.x * 128, j0 = blockIdx.y * 128;
  // staging assignment
  const int wj = tid >> 1, wk0 = (tid & 1) * 8;       // W: row wj, k's wk0..+7
  const int ak = tid >> 4, ab = (tid & 15) * 8;       // A: row ak, b's ab..+7
  const float* wsrc = fw1 + (size_t)(j0 + wj) * 1024 + wk0;
  const float* asrc = in + (size_t)ak * B + b0 + ab;

  float4 wr0 = *(const float4*)(wsrc);
  float4 wr1 = *(const float4*)(wsrc + 4);
  float4 ar0 = *(const float4*)(asrc);
  float4 ar1 = *(const float4*)(asrc + 4);

  float acc[8][8];
#pragma unroll
  for (int jr = 0; jr < 8; ++jr)
#pragma unroll
    for (int bc = 0; bc < 8; ++bc) acc[jr][bc] = 0.f;

  // stage buffer 0
#pragma unroll
  for (int i = 0; i < 4; ++i) Wt[0][wk0 + i][wj] = ((const float*)&wr0)[i];
#pragma unroll
  for (int i = 0; i < 4; ++i) Wt[0][wk0 + 4 + i][wj] = ((const float*)&wr1)[i];
  *(float4*)&At[0][ak][ab] = ar0;
  *(float4*)&At[0][ak][ab + 4] = ar1;
  __syncthreads();

  for (int t = 0; t < 64; ++t) {
    const int cur = t & 1;
    if (t < 63) {
      const float* wp = wsrc + (t + 1) * 16;
      wr0 = *(const float4*)(wp);
      wr1 = *(const float4*)(wp + 4);
      const float* ap = asrc + (size_t)(t + 1) * 16 * B;
      ar0 = *(const float4*)(ap);
      ar1 = *(const float4*)(ap + 4);
    }
#pragma unroll
    for (int k = 0; k < 16; ++k) {
      float4 wl = *(const float4*)&Wt[cur][k][ty * 4];
      float4 wh = *(const float4*)&Wt[cur][k][64 + ty * 4];
      float4 al = *(const float4*)&At[cur][k][tx * 4];
      float4 ah = *(const float4*)&At[cur][k][64 + tx * 4];
      const float wv[8] = {wl.x, wl.y, wl.z, wl.w, wh.x, wh.y, wh.z, wh.w};
      const float av[8] = {al.x, al.y, al.z, al.w, ah.x, ah.y, ah.z, ah.w};
#pragma unroll
      for (int jr = 0; jr < 8; ++jr)
#pragma unroll
        for (int bc = 0; bc < 8; ++bc)
          acc[jr][bc] = fmaf(wv[jr], av[bc], acc[jr][bc]);
    }
    if (t < 63) {
      const int nxt = cur ^ 1;
#pragma unroll
      for (int i = 0; i < 4; ++i) Wt[nxt][wk0 + i][wj] = ((const float*)&wr0)[i];
#pragma unroll
      for (int i = 0; i < 4; ++i)
        Wt[nxt][wk0 + 4 + i][wj] = ((const float*)&wr1)[i];
      *(float4*)&At[nxt][ak][ab] = ar0;
      *(float4*)&At[nxt][ak][ab + 4] = ar1;
    }
    __syncthreads();
  }

  // epilogue: bias + relu, vectorized stores
#pragma unroll
  for (int jr = 0; jr < 8; ++jr) {
    const int j = j0 + (jr < 4 ? ty * 4 + jr : 64 + ty * 4 + (jr - 4));
    const float bj = fb1[j];
    float4 lo, hi;
    lo.x = fmaxf(acc[jr][0] + bj, 0.f);
    lo.y = fmaxf(acc[jr][1] + bj, 0.f);
    lo.z = fmaxf(acc[jr][2] + bj, 0.f);
    lo.w = fmaxf(acc[jr][3] + bj, 0.f);
    hi.x = fmaxf(acc[jr][4] + bj, 0.f);
    hi.y = fmaxf(acc[jr][5] + bj, 0.f);
    hi.z = fmaxf(acc[jr][6] + bj, 0.f);
    hi.w = fmaxf(acc[jr][7] + bj, 0.f);
    *(float4*)&out[(size_t)j * B + b0 + tx * 4] = lo;
    *(float4*)&out[(size_t)j * B + b0 + 64 + tx * 4] = hi;
  }
}

// ---------------- FC2: out[b,10] = fw2[10,512] @ h4[512,B] + fb2 -----------
__global__ __launch_bounds__(256) void k_fc2(const float* __restrict__ in,
                                             const float* __restrict__ fw2,
                                             const float* __restrict__ fb2,
                                             float* __restrict__ out, int B,
                                             int b0) {
  __shared__ float red[4][10][64];
  const int tx = threadIdx.x;
  const int b = blockIdx.x * 64 + tx;
  const int tyu = RFL(threadIdx.y);
  float acc[10];
#pragma unroll
  for (int i = 0; i < 10; ++i) acc[i] = 0.f;
  for (int kk = 0; kk < 128; ++kk) {
    const int k = tyu * 128 + kk;
    const float v = in[(size_t)k * B + b];
#pragma unroll
    for (int i = 0; i < 10; ++i) acc[i] = fmaf(v, fw2[i * 512 + k], acc[i]);
  }
#pragma unroll
  for (int i = 0; i < 10; ++i) red[tyu][i][tx] = acc[i];
  __syncthreads();
  if (threadIdx.y == 0) {
#pragma unroll
    for (int i = 0; i < 10; ++i) {
      const float s = fb2[i] + red[0][i][tx] + red[1][i][tx] + red[2][i][tx] +
                      red[3][i][tx];
      out[(size_t)(b0 + b) * 10 + i] = s;
    }
  }
}

extern "C" void kernel_launch(void* const* d_in, const int* in_sizes, int n_in,
                              void* d_out, int out_size, void* d_ws,
                              size_t ws_size, hipStream_t stream) {
  const float* x   = (const float*)d_in[0];
  const float* w1  = (const float*)d_in[1];
  const float* b1  = (const float*)d_in[2];
  const float* w2  = (const float*)d_in[3];
  const float* b2  = (const float*)d_in[4];
  const float* w3  = (const float*)d_in[5];
  const float* b3  = (const float*)d_in[6];
  const float* fw1 = (const float*)d_in[7];
  const float* fb1 = (const float*)d_in[8];
  const float* fw2 = (const float*)d_in[9];
  const float* fb2 = (const float*)d_in[10];
  float* out = (float*)d_out;

  const int B = in_sizes[0] / 784;  // 8192

  const size_t per_elem = (size_t)(784 + 2704 + 1152) * sizeof(float);
  int Bc = B;
  while ((size_t)Bc * per_elem > ws_size && Bc > 512) Bc >>= 1;
  const int nch = B / Bc;

  float* P0 = (float*)d_ws;              // xT[784,Bc] then h4[512,Bc]
  float* P1 = P0 + (size_t)784 * Bc;     // h1[2704,Bc] then h3[1024,Bc]
  float* P2 = P1 + (size_t)2704 * Bc;    // h2[1152,Bc]

  for (int ch = 0; ch < nch; ++ch) {
    const float* xc = x + (size_t)ch * Bc * 784;
    const int b0 = ch * Bc;
    const int nb = Bc / 64;

    k_tr<<<dim3(Bc / 32, 25), dim3(32, 8), 0, stream>>>(xc, P0, Bc);
    k_lc1<<<dim3(nb, 13), dim3(64, 4), 0, stream>>>(P0, w1, b1, P1, Bc);
    k_lc2<<<dim3(nb, 4), dim3(64, 4), 0, stream>>>(P1, w2, b2, P2, Bc);
    k_lc3<<<dim3(nb, 4), dim3(64, 4), 0, stream>>>(P2, w3, b3, P1, Bc);
    k_fc1<<<dim3(Bc / 128, 4), dim3(256), 0, stream>>>(P1, fw1, fb1, P0, Bc);
    k_fc2<<<dim3(nb), dim3(64, 4), 0, stream>>>(P0, fw2, fb2, out, Bc, b0);
  }
}

// Round 4
// 646.687 us; speedup vs baseline: 3.4673x; 1.1239x over previous
//
#include <hip/hip_runtime.h>

#define RFL(x) __builtin_amdgcn_readfirstlane((int)(x))

// Activations in batch-last layout [feature, B]; lanes = batch (coalesced).

// ---------------- transpose x[B,784] -> xT[784, Bc] ----------------
__global__ __launch_bounds__(256) void k_tr(const float* __restrict__ x,
                                            float* __restrict__ xT, int Bc) {
  __shared__ float t[32][33];
  const int b0 = blockIdx.x * 32;
  const int f0 = blockIdx.y * 32;
  const int tx = threadIdx.x, ty = threadIdx.y;
  for (int r = ty; r < 32; r += 8) {
    const int f = f0 + tx;
    t[r][tx] = (f < 784) ? x[(size_t)(b0 + r) * 784 + f] : 0.f;
  }
  __syncthreads();
  for (int r = ty; r < 32; r += 8) {
    const int f = f0 + r;
    if (f < 784) xT[(size_t)f * Bc + b0 + tx] = t[tx][r];
  }
}

// ---------------- LC1: [1,28,28] -> [16,13,13], stride 2, relu -------------
__global__ __launch_bounds__(256) void k_lc1(const float* __restrict__ in,
                                             const float* __restrict__ w,
                                             const float* __restrict__ bias,
                                             float* __restrict__ out, int B) {
  const int b = blockIdx.x * 64 + threadIdx.x;
  const int ho = blockIdx.y;
  const int o0 = RFL(threadIdx.y) * 4;
  float xv[3][27];
#pragma unroll
  for (int r = 0; r < 3; ++r)
#pragma unroll
    for (int col = 0; col < 27; ++col)
      xv[r][col] = in[(size_t)((2 * ho + r) * 28 + col) * B + b];
  float acc[4][13];
#pragma unroll
  for (int oo = 0; oo < 4; ++oo)
#pragma unroll
    for (int wo = 0; wo < 13; ++wo)
      acc[oo][wo] = bias[(o0 + oo) * 169 + ho * 13 + wo];
#pragma unroll
  for (int oo = 0; oo < 4; ++oo)
#pragma unroll
    for (int wo = 0; wo < 13; ++wo) {
      const float* wp = w + (size_t)((o0 + oo) * 169 + ho * 13 + wo) * 9;
#pragma unroll
      for (int kh = 0; kh < 3; ++kh)
#pragma unroll
        for (int kw = 0; kw < 3; ++kw)
          acc[oo][wo] = fmaf(xv[kh][2 * wo + kw], wp[kh * 3 + kw], acc[oo][wo]);
    }
#pragma unroll
  for (int oo = 0; oo < 4; ++oo)
#pragma unroll
    for (int wo = 0; wo < 13; ++wo)
      out[(size_t)((o0 + oo) * 169 + ho * 13 + wo) * B + b] =
          fmaxf(acc[oo][wo], 0.f);
}

// ---------------- LC2: [16,13,13] -> [32,6,6], stride 2, relu --------------
// grid (64 btile, 8 = oblk*2+hh), block (64,4). Lane = 2 batches (float2).
// Per c: stage 7 rows x 13 cols x 128 b into LDS (46.6 KB), all 4 waves share.
// Wave = 2 o; block = 8 o; hh selects ho half {0..2}/{3..5}.
__global__ __launch_bounds__(256) void k_lc2(const float* __restrict__ in,
                                             const float* __restrict__ w,
                                             const float* __restrict__ bias,
                                             float* __restrict__ out, int B) {
  __shared__ float Xs[7 * 13 * 128];  // [row][col][b]
  const int lane = threadIdx.x;
  const int wv = threadIdx.y;
  const int tid = wv * 64 + lane;
  const int b0 = blockIdx.x * 128;
  const int oblk = blockIdx.y >> 1, hh = blockIdx.y & 1;
  const int obase = oblk * 8 + wv * 2;
  const int row0 = hh * 6;

  float acc[2][18][2];
#pragma unroll
  for (int oo = 0; oo < 2; ++oo)
#pragma unroll
    for (int p = 0; p < 18; ++p) {
      const float bz = bias[(obase + oo) * 36 + hh * 18 + p];
      acc[oo][p][0] = bz;
      acc[oo][p][1] = bz;
    }

#pragma unroll 1
  for (int c = 0; c < 16; ++c) {
    float4 v[12];
#pragma unroll
    for (int i = 0; i < 12; ++i) {
      const int f4 = tid + i * 256;  // < 2912 = 7*13*32
      if (f4 < 2912) {
        const int row = f4 / 416;  // 13*32
        const int rem = f4 - row * 416;
        const int col = rem >> 5, bq = rem & 31;
        v[i] = *(const float4*)&in[(size_t)(c * 169 + (row0 + row) * 13 + col) *
                                       B +
                                   b0 + bq * 4];
      }
    }
    __syncthreads();  // previous compute done reading Xs
#pragma unroll
    for (int i = 0; i < 12; ++i) {
      const int f4 = tid + i * 256;
      if (f4 < 2912) *(float4*)&Xs[f4 * 4] = v[i];
    }
    __syncthreads();
#pragma unroll
    for (int hl = 0; hl < 3; ++hl) {
      float2 xv[3][13];
#pragma unroll
      for (int kh = 0; kh < 3; ++kh)
#pragma unroll
        for (int col = 0; col < 13; ++col)
          xv[kh][col] =
              *(const float2*)&Xs[((2 * hl + kh) * 13 + col) * 128 + 2 * lane];
#pragma unroll
      for (int oo = 0; oo < 2; ++oo) {
        const float* wp =
            w + (((size_t)(obase + oo) * 16 + c) * 36 + (hh * 3 + hl) * 6) * 9;
#pragma unroll
        for (int wo = 0; wo < 6; ++wo) {
          float a0 = acc[oo][hl * 6 + wo][0];
          float a1 = acc[oo][hl * 6 + wo][1];
#pragma unroll
          for (int kh = 0; kh < 3; ++kh)
#pragma unroll
            for (int kw = 0; kw < 3; ++kw) {
              const float wt = wp[wo * 9 + kh * 3 + kw];
              a0 = fmaf(xv[kh][2 * wo + kw].x, wt, a0);
              a1 = fmaf(xv[kh][2 * wo + kw].y, wt, a1);
            }
          acc[oo][hl * 6 + wo][0] = a0;
          acc[oo][hl * 6 + wo][1] = a1;
        }
      }
    }
  }
#pragma unroll
  for (int oo = 0; oo < 2; ++oo)
#pragma unroll
    for (int p = 0; p < 18; ++p) {
      float2 r;
      r.x = fmaxf(acc[oo][p][0], 0.f);
      r.y = fmaxf(acc[oo][p][1], 0.f);
      *(float2*)&out[(size_t)((obase + oo) * 36 + hh * 18 + p) * B + b0 +
                     2 * lane] = r;
    }
}

// ---------------- LC3: [32,6,6] -> [64,4,4], stride 1, no relu -------------
// grid (64 btile, 8 oblk), block (64,4). Lane = 2 batches. Per c: stage full
// 6x6 plane x 128 b (18.4 KB). Wave = 2 o; block = 8 o; all 16 positions.
__global__ __launch_bounds__(256) void k_lc3(const float* __restrict__ in,
                                             const float* __restrict__ w,
                                             const float* __restrict__ bias,
                                             float* __restrict__ out, int B) {
  __shared__ float Xs[36 * 128];
  const int lane = threadIdx.x;
  const int wv = threadIdx.y;
  const int tid = wv * 64 + lane;
  const int b0 = blockIdx.x * 128;
  const int obase = blockIdx.y * 8 + wv * 2;

  float acc[2][16][2];
#pragma unroll
  for (int oo = 0; oo < 2; ++oo)
#pragma unroll
    for (int p = 0; p < 16; ++p) {
      const float bz = bias[(obase + oo) * 16 + p];
      acc[oo][p][0] = bz;
      acc[oo][p][1] = bz;
    }

#pragma unroll 1
  for (int c = 0; c < 32; ++c) {
    float4 v[5];
#pragma unroll
    for (int i = 0; i < 5; ++i) {
      const int f4 = tid + i * 256;  // < 1152 = 36*32
      if (f4 < 1152) {
        const int pos = f4 >> 5, bq = f4 & 31;
        v[i] = *(const float4*)&in[(size_t)(c * 36 + pos) * B + b0 + bq * 4];
      }
    }
    __syncthreads();
#pragma unroll
    for (int i = 0; i < 5; ++i) {
      const int f4 = tid + i * 256;
      if (f4 < 1152) *(float4*)&Xs[f4 * 4] = v[i];
    }
    __syncthreads();
#pragma unroll
    for (int ho = 0; ho < 4; ++ho) {
      float2 xv[3][6];
#pragma unroll
      for (int kh = 0; kh < 3; ++kh)
#pragma unroll
        for (int col = 0; col < 6; ++col)
          xv[kh][col] =
              *(const float2*)&Xs[((ho + kh) * 6 + col) * 128 + 2 * lane];
#pragma unroll
      for (int oo = 0; oo < 2; ++oo) {
        const float* wp =
            w + (((size_t)(obase + oo) * 32 + c) * 16 + ho * 4) * 9;
#pragma unroll
        for (int wo = 0; wo < 4; ++wo) {
          float a0 = acc[oo][ho * 4 + wo][0];
          float a1 = acc[oo][ho * 4 + wo][1];
#pragma unroll
          for (int kh = 0; kh < 3; ++kh)
#pragma unroll
            for (int kw = 0; kw < 3; ++kw) {
              const float wt = wp[wo * 9 + kh * 3 + kw];
              a0 = fmaf(xv[kh][wo + kw].x, wt, a0);
              a1 = fmaf(xv[kh][wo + kw].y, wt, a1);
            }
          acc[oo][ho * 4 + wo][0] = a0;
          acc[oo][ho * 4 + wo][1] = a1;
        }
      }
    }
  }
#pragma unroll
  for (int oo = 0; oo < 2; ++oo)
#pragma unroll
    for (int p = 0; p < 16; ++p) {
      float2 r;
      r.x = acc[oo][p][0];
      r.y = acc[oo][p][1];
      *(float2*)&out[(size_t)((obase + oo) * 16 + p) * B + b0 + 2 * lane] = r;
    }
}

// ---------------- FC1: SGEMM h4[512,B] = relu(fw1[512,1024] @ h3[1024,B]) --
__global__ __launch_bounds__(256) void k_fc1(const float* __restrict__ in,
                                             const float* __restrict__ fw1,
                                             const float* __restrict__ fb1,
                                             float* __restrict__ out, int B) {
  __shared__ float Wt[2][16][128];
  __shared__ float At[2][16][128];
  const int tid = threadIdx.x;
  const int tx = tid & 15, ty = tid >> 4;
  const int b0 = blockIdx.x * 128, j0 = blockIdx.y * 128;
  const int wj = tid >> 1, wk0 = (tid & 1) * 8;
  const int ak = tid >> 4, ab = (tid & 15) * 8;
  const float* wsrc = fw1 + (size_t)(j0 + wj) * 1024 + wk0;
  const float* asrc = in + (size_t)ak * B + b0 + ab;

  float4 wr0 = *(const float4*)(wsrc);
  float4 wr1 = *(const float4*)(wsrc + 4);
  float4 ar0 = *(const float4*)(asrc);
  float4 ar1 = *(const float4*)(asrc + 4);

  float acc[8][8];
#pragma unroll
  for (int jr = 0; jr < 8; ++jr)
#pragma unroll
    for (int bc = 0; bc < 8; ++bc) acc[jr][bc] = 0.f;

#pragma unroll
  for (int i = 0; i < 4; ++i) Wt[0][wk0 + i][wj] = ((const float*)&wr0)[i];
#pragma unroll
  for (int i = 0; i < 4; ++i) Wt[0][wk0 + 4 + i][wj] = ((const float*)&wr1)[i];
  *(float4*)&At[0][ak][ab] = ar0;
  *(float4*)&At[0][ak][ab + 4] = ar1;
  __syncthreads();

  for (int t = 0; t < 64; ++t) {
    const int cur = t & 1;
    if (t < 63) {
      const float* wp = wsrc + (t + 1) * 16;
      wr0 = *(const float4*)(wp);
      wr1 = *(const float4*)(wp + 4);
      const float* ap = asrc + (size_t)(t + 1) * 16 * B;
      ar0 = *(const float4*)(ap);
      ar1 = *(const float4*)(ap + 4);
    }
#pragma unroll
    for (int k = 0; k < 16; ++k) {
      float4 wl = *(const float4*)&Wt[cur][k][ty * 4];
      float4 wh = *(const float4*)&Wt[cur][k][64 + ty * 4];
      float4 al = *(const float4*)&At[cur][k][tx * 4];
      float4 ah = *(const float4*)&At[cur][k][64 + tx * 4];
      const float wv[8] = {wl.x, wl.y, wl.z, wl.w, wh.x, wh.y, wh.z, wh.w};
      const float av[8] = {al.x, al.y, al.z, al.w, ah.x, ah.y, ah.z, ah.w};
#pragma unroll
      for (int jr = 0; jr < 8; ++jr)
#pragma unroll
        for (int bc = 0; bc < 8; ++bc)
          acc[jr][bc] = fmaf(wv[jr], av[bc], acc[jr][bc]);
    }
    if (t < 63) {
      const int nxt = cur ^ 1;
#pragma unroll
      for (int i = 0; i < 4; ++i) Wt[nxt][wk0 + i][wj] = ((const float*)&wr0)[i];
#pragma unroll
      for (int i = 0; i < 4; ++i)
        Wt[nxt][wk0 + 4 + i][wj] = ((const float*)&wr1)[i];
      *(float4*)&At[nxt][ak][ab] = ar0;
      *(float4*)&At[nxt][ak][ab + 4] = ar1;
    }
    __syncthreads();
  }

#pragma unroll
  for (int jr = 0; jr < 8; ++jr) {
    const int j = j0 + (jr < 4 ? ty * 4 + jr : 64 + ty * 4 + (jr - 4));
    const float bj = fb1[j];
    float4 lo, hi;
    lo.x = fmaxf(acc[jr][0] + bj, 0.f);
    lo.y = fmaxf(acc[jr][1] + bj, 0.f);
    lo.z = fmaxf(acc[jr][2] + bj, 0.f);
    lo.w = fmaxf(acc[jr][3] + bj, 0.f);
    hi.x = fmaxf(acc[jr][4] + bj, 0.f);
    hi.y = fmaxf(acc[jr][5] + bj, 0.f);
    hi.z = fmaxf(acc[jr][6] + bj, 0.f);
    hi.w = fmaxf(acc[jr][7] + bj, 0.f);
    *(float4*)&out[(size_t)j * B + b0 + tx * 4] = lo;
    *(float4*)&out[(size_t)j * B + b0 + 64 + tx * 4] = hi;
  }
}

// ---------------- FC2: out[b,10] = fw2[10,512] @ h4[512,B] + fb2 -----------
__global__ __launch_bounds__(256) void k_fc2(const float* __restrict__ in,
                                             const float* __restrict__ fw2,
                                             const float* __restrict__ fb2,
                                             float* __restrict__ out, int B,
                                             int b0) {
  __shared__ float red[4][10][64];
  const int tx = threadIdx.x;
  const int b = blockIdx.x * 64 + tx;
  const int tyu = RFL(threadIdx.y);
  float acc[10];
#pragma unroll
  for (int i = 0; i < 10; ++i) acc[i] = 0.f;
  for (int kk = 0; kk < 128; ++kk) {
    const int k = tyu * 128 + kk;
    const float v = in[(size_t)k * B + b];
#pragma unroll
    for (int i = 0; i < 10; ++i) acc[i] = fmaf(v, fw2[i * 512 + k], acc[i]);
  }
#pragma unroll
  for (int i = 0; i < 10; ++i) red[tyu][i][tx] = acc[i];
  __syncthreads();
  if (threadIdx.y == 0) {
#pragma unroll
    for (int i = 0; i < 10; ++i) {
      const float s = fb2[i] + red[0][i][tx] + red[1][i][tx] + red[2][i][tx] +
                      red[3][i][tx];
      out[(size_t)(b0 + b) * 10 + i] = s;
    }
  }
}

extern "C" void kernel_launch(void* const* d_in, const int* in_sizes, int n_in,
                              void* d_out, int out_size, void* d_ws,
                              size_t ws_size, hipStream_t stream) {
  const float* x   = (const float*)d_in[0];
  const float* w1  = (const float*)d_in[1];
  const float* b1  = (const float*)d_in[2];
  const float* w2  = (const float*)d_in[3];
  const float* b2  = (const float*)d_in[4];
  const float* w3  = (const float*)d_in[5];
  const float* b3  = (const float*)d_in[6];
  const float* fw1 = (const float*)d_in[7];
  const float* fb1 = (const float*)d_in[8];
  const float* fw2 = (const float*)d_in[9];
  const float* fb2 = (const float*)d_in[10];
  float* out = (float*)d_out;

  const int B = in_sizes[0] / 784;  // 8192

  const size_t per_elem = (size_t)(784 + 2704 + 1152) * sizeof(float);
  int Bc = B;
  while ((size_t)Bc * per_elem > ws_size && Bc > 512) Bc >>= 1;
  const int nch = B / Bc;

  float* P0 = (float*)d_ws;              // xT[784,Bc] then h4[512,Bc]
  float* P1 = P0 + (size_t)784 * Bc;     // h1[2704,Bc] then h3[1024,Bc]
  float* P2 = P1 + (size_t)2704 * Bc;    // h2[1152,Bc]

  for (int ch = 0; ch < nch; ++ch) {
    const float* xc = x + (size_t)ch * Bc * 784;
    const int b0 = ch * Bc;
    const int nb = Bc / 64;

    k_tr<<<dim3(Bc / 32, 25), dim3(32, 8), 0, stream>>>(xc, P0, Bc);
    k_lc1<<<dim3(nb, 13), dim3(64, 4), 0, stream>>>(P0, w1, b1, P1, Bc);
    k_lc2<<<dim3(Bc / 128, 8), dim3(64, 4), 0, stream>>>(P1, w2, b2, P2, Bc);
    k_lc3<<<dim3(Bc / 128, 8), dim3(64, 4), 0, stream>>>(P2, w3, b3, P1, Bc);
    k_fc1<<<dim3(Bc / 128, 4), dim3(256), 0, stream>>>(P1, fw1, fb1, P0, Bc);
    k_fc2<<<dim3(nb), dim3(64, 4), 0, stream>>>(P0, fw2, fb2, out, Bc, b0);
  }
}